// Round 6
// baseline (327.825 us; speedup 1.0000x reference)
//
#include <hip/hip_runtime.h>
#include <hip/hip_bf16.h>
#include <hip/hip_cooperative_groups.h>
#include <cstdint>
#include <math.h>

namespace cg = cooperative_groups;

// Problem constants
#define SEQ    2048
#define DMODEL 1024
#define NHEAD  16
#define DHEAD  64
#define NZPAD  32   // per-row nonzero count padded to 32 (analytic max = 26)

#define CAST_BLOCKS 3072
#define TR_BLOCKS   4096
#define PREP_WORK   (CAST_BLOCKS + TR_BLOCKS)
#define PROJ_TILES  768
#define ATTN_TILES  (NHEAD * SEQ / 4)   // 8192
#define FINAL_TILES 512

typedef __bf16 bf16;
typedef __bf16 bf16x8 __attribute__((ext_vector_type(8)));
typedef float  f32x4  __attribute__((ext_vector_type(4)));

typedef __attribute__((address_space(3))) uint32_t lds_u32;
typedef __attribute__((address_space(1))) const uint32_t global_u32;

__device__ __forceinline__ void async_load16(const void* g, void* l) {
    __builtin_amdgcn_global_load_lds((global_u32*)g, (lds_u32*)l, 16, 0, 0);
}

// Analytic sparse-layout support for ORIGIN_SHAPE=(8,16,16), LOCAL_BLOCKS=3:
// support(s) = {t'*256 + (s&255), t'<t} u {(s&0x700) + h'*16 + (s&15), h'<h}
//            u {s-win..s}, win = min(s,3); disjoint; cnt = t+h+win+1 <= 26.
__device__ __forceinline__ int support_idx(int s, int c, int tt, int hh,
                                           int cnt) {
    const int jA = c * 256 + (s & 255);                    // axial-T, c < tt
    const int jB = (s & 0x700) + (c - tt) * 16 + (s & 15); // axial-H
    const int jC = s - (cnt - 1 - c);                      // causal window
    return c < tt ? jA : (c < tt + hh ? jB : (c < cnt ? jC : s));
}

// ===========================================================================
// Phase bodies (shared between the cooperative mega-kernel and the
// 4-kernel fallback path). LDS is passed as a raw byte pointer; the mega
// kernel carves one 48KB block, standalone kernels size their own.
// ===========================================================================

// ---- P1: fp32->bf16 casts (wid<3072) + weight transpose-casts ------------
__device__ __forceinline__ void prep_work(
    int wid, const float* __restrict__ q, const float* __restrict__ k,
    const float* __restrict__ v,
    bf16* __restrict__ qx, bf16* __restrict__ kx, bf16* __restrict__ vx,
    const float* __restrict__ w0, const float* __restrict__ w1,
    const float* __restrict__ w2, const float* __restrict__ w3,
    bf16* __restrict__ t0, bf16* __restrict__ t1,
    bf16* __restrict__ t2, bf16* __restrict__ t3, char* ldsraw) {
    if (wid < CAST_BLOCKS) {
        const int z = wid >> 10;
        const float* src = (z == 0) ? q : (z == 1) ? k : v;
        bf16* dst        = (z == 0) ? qx : (z == 1) ? kx : vx;
        const int i = (wid & 1023) * 256 + threadIdx.x;
        const float4* s4 = (const float4*)src;
        float4 a = s4[i * 2 + 0];
        float4 b = s4[i * 2 + 1];
        bf16x8 o;
        o[0] = (bf16)a.x; o[1] = (bf16)a.y; o[2] = (bf16)a.z; o[3] = (bf16)a.w;
        o[4] = (bf16)b.x; o[5] = (bf16)b.y; o[6] = (bf16)b.z; o[7] = (bf16)b.w;
        ((bf16x8*)dst)[i] = o;
    } else {
        float (*tile)[33] = (float(*)[33])ldsraw;
        const int b = wid - CAST_BLOCKS;
        const int z = b >> 10, rem = b & 1023;
        const float* w = (z == 0) ? w0 : (z == 1) ? w1 : (z == 2) ? w2 : w3;
        bf16* t        = (z == 0) ? t0 : (z == 1) ? t1 : (z == 2) ? t2 : t3;
        const int tx = threadIdx.x & 31, ty = threadIdx.x >> 5;
        const int kbase = (rem >> 5) * 32, nbase = (rem & 31) * 32;
#pragma unroll
        for (int i = 0; i < 4; ++i)
            tile[ty + 8 * i][tx] = w[(size_t)(kbase + ty + 8 * i) * DMODEL + nbase + tx];
        __syncthreads();
#pragma unroll
        for (int i = 0; i < 4; ++i)
            t[(size_t)(nbase + ty + 8 * i) * DMODEL + kbase + tx] = (bf16)tile[tx][ty + 8 * i];
        __syncthreads();   // tile[] reused by the next grid-stride iteration
    }
}

// ---- P2: one 64x128 proj tile. n-ALIGNED XCD partition: xcd = tidx&7 owns
// n-columns [xcd*128,(xcd+1)*128) for all z,m -> the qp/kp/vp column-slices
// this XCD writes are exactly the head-pair slices it reads in P3 (1.5MB,
// written at tile end, stays in its private L2 across grid.sync). A-tiles
// are read exactly once per XCD (96 tiles = 3z x 32m x 1n, no redundancy).
__device__ __forceinline__ void proj3_tile(
    int tidx, const bf16* __restrict__ qx, const bf16* __restrict__ kx,
    const bf16* __restrict__ vx,
    const bf16* __restrict__ wqT, const bf16* __restrict__ wkT,
    const bf16* __restrict__ wvT,
    const float* __restrict__ bq, const float* __restrict__ bk,
    const float* __restrict__ bv,
    bf16* __restrict__ qp, bf16* __restrict__ kp, bf16* __restrict__ vp,
    char* lds) {
    constexpr int K = 1024, N = 1024, BK = 64, TM = 64, MI = 2;
    constexpr int ACH = TM * (BK / 8);        // 512 chunks
    constexpr int TCH = ACH + 128 * (BK / 8); // 1536 chunks -> 6 per thread

    const int n0 = (tidx & 7) * 128;          // XCD-aligned n column
    const int q_ = tidx >> 3;                 // 0..95
    const int z  = q_ >> 5;
    const int m0 = (q_ & 31) * TM;

    const bf16* A   = (z == 0) ? qx : (z == 1) ? kx : vx;
    const bf16* BT  = (z == 0) ? wqT : (z == 1) ? wkT : wvT;
    const float* bi = (z == 0) ? bq : (z == 1) ? bk : bv;
    bf16* C         = (z == 0) ? qp : (z == 1) ? kp : vp;

    const int tid = threadIdx.x;
    const int w = tid >> 6, lane = tid & 63;
    const int wm = w >> 1, wn = w & 1;
    const int lr = lane & 15, quad = lane >> 4;

    auto sAb = [&](int buf) { return lds + buf * (TM * BK * 2); };          // 2x8KB
    auto sBb = [&](int buf) { return lds + 16384 + buf * (128 * BK * 2); }; // 2x16KB

    f32x4 acc[MI][4] = {};
    float bia[4];
#pragma unroll
    for (int ni = 0; ni < 4; ++ni) bia[ni] = bi[n0 + wn * 64 + ni * 16 + lr];

    auto stage = [&](int buf, int kt) {
#pragma unroll
        for (int kk = 0; kk < TCH / 256; ++kk) {
            const int cb = kk * 256 + w * 64;     // wave-uniform chunk base
            const int p  = cb + lane;             // linear LDS slot
            if (cb < ACH) {
                const int row = p >> 3, chl = p & 7;
                const int chg = chl ^ (row & 7);  // inverse-swizzled source
                async_load16(A + (size_t)(m0 + row) * K + kt + chg * 8,
                             sAb(buf) + cb * 16);
            } else {
                const int p2 = p - ACH, row = p2 >> 3, chl = p2 & 7;
                const int chg = chl ^ (row & 7);
                async_load16(BT + (size_t)(n0 + row) * K + kt + chg * 8,
                             sBb(buf) + (cb - ACH) * 16);
            }
        }
    };

    stage(0, 0);
    stage(1, BK);
    int cur = 0;
    for (int kt = 0; kt < K; kt += BK) {
        if (kt + BK < K) {
            asm volatile("s_waitcnt vmcnt(6)" ::: "memory");  // cur tile landed
        } else {
            asm volatile("s_waitcnt vmcnt(0)" ::: "memory");  // epilogue drain
        }
        __builtin_amdgcn_s_barrier();
        __builtin_amdgcn_sched_barrier(0);
#pragma unroll
        for (int ks = 0; ks < 2; ++ks) {          // two 16x16x32 k-substeps
            bf16x8 af[MI], bfr[4];
#pragma unroll
            for (int mi = 0; mi < MI; ++mi) {
                const int row = wm * (TM / 2) + mi * 16 + lr;
                af[mi] = *(const bf16x8*)
                    (sAb(cur) + row * (BK * 2) + (((ks * 4 + quad) ^ (row & 7)) * 16));
            }
#pragma unroll
            for (int ni = 0; ni < 4; ++ni) {
                const int row = wn * 64 + ni * 16 + lr;
                bfr[ni] = *(const bf16x8*)
                    (sBb(cur) + row * (BK * 2) + (((ks * 4 + quad) ^ (row & 7)) * 16));
            }
            __builtin_amdgcn_s_setprio(1);
#pragma unroll
            for (int mi = 0; mi < MI; ++mi)
#pragma unroll
                for (int ni = 0; ni < 4; ++ni)
                    acc[mi][ni] = __builtin_amdgcn_mfma_f32_16x16x32_bf16(
                        af[mi], bfr[ni], acc[mi][ni], 0, 0, 0);
            __builtin_amdgcn_s_setprio(0);
        }
        __builtin_amdgcn_s_barrier();             // all waves done reading cur
        __builtin_amdgcn_sched_barrier(0);
        if (kt + 2 * BK < K) stage(cur, kt + 2 * BK);
        cur ^= 1;
    }

#pragma unroll
    for (int mi = 0; mi < MI; ++mi)
#pragma unroll
        for (int ni = 0; ni < 4; ++ni) {
            const int row = m0 + wm * (TM / 2) + mi * 16 + quad * 4;
            const int col = n0 + wn * 64 + ni * 16 + lr;
            const f32x4 vv = acc[mi][ni];
#pragma unroll
            for (int r = 0; r < 4; ++r)
                C[(size_t)(row + r) * N + col] = (bf16)(vv[r] + bia[ni]);
        }
}

// ---- P3: one attn virtual block (4 (h,s) waves) --------------------------
__device__ __forceinline__ void attn_tile(
    int vb, const bf16* __restrict__ qp, const bf16* __restrict__ kp,
    const bf16* __restrict__ vp, bf16* __restrict__ ao) {
    const int wv = threadIdx.x >> 6, lane = threadIdx.x & 63;
    const int bid = (vb & 7) * (ATTN_TILES >> 3) + (vb >> 3);  // XCD chunk
    const int p = bid * 4 + wv;
    const int s = __builtin_amdgcn_readfirstlane(p & (SEQ - 1));
    const int h = __builtin_amdgcn_readfirstlane(p >> 11);
    const int hbase = h * DHEAD;
    const int hoff = hbase + lane;

    const int tt = (s >> 8) & 7, hh = (s >> 4) & 15;
    const int win = (s < 3) ? s : 3;
    const int cnt = tt + hh + win + 1;

    int t[NZPAD];                                 // s-uniform -> scalar regs
#pragma unroll
    for (int c = 0; c < NZPAD; ++c) t[c] = support_idx(s, c, tt, hh, cnt);

    const int c_lane = lane & 31;
    const int fo = (lane >> 5) << 5;              // feature offset: 0 or 32
    const int myT = support_idx(s, c_lane, tt, hh, cnt);

    const bf16x8* qrow = (const bf16x8*)(qp + (size_t)s * DMODEL + hbase + fo);
    const bf16x8* krow = (const bf16x8*)(kp + (size_t)myT * DMODEL + hbase + fo);
    bf16x8 qc[4], kc[4];
#pragma unroll
    for (int j = 0; j < 4; ++j) { qc[j] = qrow[j]; kc[j] = krow[j]; }

    float vvv[NZPAD];
#pragma unroll
    for (int c = 0; c < NZPAD; ++c)
        vvv[c] = (float)vp[(size_t)t[c] * DMODEL + hoff];

    float dot = 0.f;
    __builtin_amdgcn_s_setprio(1);
#pragma unroll
    for (int j = 0; j < 4; ++j)
#pragma unroll
        for (int e = 0; e < 8; ++e)
            dot = fmaf((float)qc[j][e], (float)kc[j][e], dot);
    __builtin_amdgcn_s_setprio(0);
    dot += __shfl_xor(dot, 32);

    const float logit = (c_lane < cnt) ? dot * 0.125f : -1e30f;  // 1/sqrt(64)
    float m = logit;
    m = fmaxf(m, __shfl_xor(m, 1)); m = fmaxf(m, __shfl_xor(m, 2));
    m = fmaxf(m, __shfl_xor(m, 4)); m = fmaxf(m, __shfl_xor(m, 8));
    m = fmaxf(m, __shfl_xor(m, 16));
    const float e = __expf(logit - m);
    float ssum = e;
    ssum += __shfl_xor(ssum, 1); ssum += __shfl_xor(ssum, 2);
    ssum += __shfl_xor(ssum, 4); ssum += __shfl_xor(ssum, 8);
    ssum += __shfl_xor(ssum, 16);
    const float prob = e / ssum;

    float acc = 0.f;
    __builtin_amdgcn_s_setprio(1);
#pragma unroll
    for (int c = 0; c < NZPAD; ++c) {
        const float pc = __uint_as_float(
            __builtin_amdgcn_readlane(__float_as_uint(prob), c));
        acc = fmaf(pc, vvv[c], acc);
    }
    __builtin_amdgcn_s_setprio(0);
    ao[(size_t)s * DMODEL + hoff] = (bf16)acc;
}

// ---- P4: one 32x128 final-GEMM tile (fp32 out) ---------------------------
__device__ __forceinline__ void final_tile(
    int orig, const bf16* __restrict__ A, const bf16* __restrict__ BT,
    const float* __restrict__ bias, float* __restrict__ C, char* lds) {
    constexpr int K = 1024, N = 1024, BK = 64, TM = 32, MI = 2;
    constexpr int ACH = TM * (BK / 8);        // 256 chunks
    constexpr int TCH = ACH + 128 * (BK / 8); // 1280 chunks -> 5 per thread

    const int flat = (orig & 7) * 64 + (orig >> 3);   // XCD-chunked decode
    const int m0 = (flat >> 3) * TM, n0 = (flat & 7) * 128;

    const int tid = threadIdx.x;
    const int w = tid >> 6, lane = tid & 63;  // 1x4 wave grid (wn = w)
    const int lr = lane & 15, quad = lane >> 4;

    auto sAb = [&](int buf) { return lds + buf * (TM * BK * 2); };          // 2x4KB
    auto sBb = [&](int buf) { return lds + 16384 + buf * (128 * BK * 2); }; // 2x16KB

    f32x4 acc[MI][2] = {};
    float bia[2];
#pragma unroll
    for (int ni = 0; ni < 2; ++ni) bia[ni] = bias[n0 + w * 32 + ni * 16 + lr];

    auto stage = [&](int buf, int kt) {
#pragma unroll
        for (int kk = 0; kk < TCH / 256; ++kk) {
            const int cb = kk * 256 + w * 64;
            const int p = cb + lane;
            if (cb < ACH) {
                const int row = p >> 3, chl = p & 7;
                const int chg = chl ^ (row & 7);
                async_load16(A + (size_t)(m0 + row) * K + kt + chg * 8,
                             sAb(buf) + cb * 16);
            } else {
                const int p2 = p - ACH, row = p2 >> 3, chl = p2 & 7;
                const int chg = chl ^ (row & 7);
                async_load16(BT + (size_t)(n0 + row) * K + kt + chg * 8,
                             sBb(buf) + (cb - ACH) * 16);
            }
        }
    };

    stage(0, 0);
    stage(1, BK);
    int cur = 0;
    for (int kt = 0; kt < K; kt += BK) {
        if (kt + BK < K) {
            asm volatile("s_waitcnt vmcnt(5)" ::: "memory");
        } else {
            asm volatile("s_waitcnt vmcnt(0)" ::: "memory");
        }
        __builtin_amdgcn_s_barrier();
        __builtin_amdgcn_sched_barrier(0);
#pragma unroll
        for (int ks = 0; ks < 2; ++ks) {
            bf16x8 af[MI], bfr[2];
#pragma unroll
            for (int mi = 0; mi < MI; ++mi) {
                const int row = mi * 16 + lr;
                af[mi] = *(const bf16x8*)
                    (sAb(cur) + row * (BK * 2) + (((ks * 4 + quad) ^ (row & 7)) * 16));
            }
#pragma unroll
            for (int ni = 0; ni < 2; ++ni) {
                const int row = w * 32 + ni * 16 + lr;
                bfr[ni] = *(const bf16x8*)
                    (sBb(cur) + row * (BK * 2) + (((ks * 4 + quad) ^ (row & 7)) * 16));
            }
            __builtin_amdgcn_s_setprio(1);
#pragma unroll
            for (int mi = 0; mi < MI; ++mi)
#pragma unroll
                for (int ni = 0; ni < 2; ++ni)
                    acc[mi][ni] = __builtin_amdgcn_mfma_f32_16x16x32_bf16(
                        af[mi], bfr[ni], acc[mi][ni], 0, 0, 0);
            __builtin_amdgcn_s_setprio(0);
        }
        __builtin_amdgcn_s_barrier();
        __builtin_amdgcn_sched_barrier(0);
        if (kt + 2 * BK < K) stage(cur, kt + 2 * BK);
        cur ^= 1;
    }

#pragma unroll
    for (int mi = 0; mi < MI; ++mi)
#pragma unroll
        for (int ni = 0; ni < 2; ++ni) {
            const int row = m0 + mi * 16 + quad * 4;
            const int col = n0 + w * 32 + ni * 16 + lr;
            const f32x4 vv = acc[mi][ni];
#pragma unroll
            for (int r = 0; r < 4; ++r)
                C[(size_t)(row + r) * N + col] = vv[r] + bia[ni];
        }
}

// ===========================================================================
// Cooperative mega-kernel: 4 phases, grid.sync() between. All phases
// grid-stride, so any co-resident grid size is correct. LDS 48KB -> 3
// blocks/CU -> grid 768 expected (= exactly proj3's tile count).
// ===========================================================================
__global__ __launch_bounds__(256) void mega_kernel(
    const float* query, const float* key, const float* value,
    const float* wq, const float* wk, const float* wv, const float* wo,
    const float* bq, const float* bk, const float* bv, const float* bo,
    bf16* qx, bf16* kx, bf16* vx,
    bf16* wqT, bf16* wkT, bf16* wvT, bf16* woT,
    bf16* qp, bf16* kp, bf16* vp, bf16* ao, float* out) {
    __shared__ __align__(16) char lds[49152];
    cg::grid_group grid = cg::this_grid();
    const int G = gridDim.x;

    for (int wid = blockIdx.x; wid < PREP_WORK; wid += G)
        prep_work(wid, query, key, value, qx, kx, vx,
                  wq, wk, wv, wo, wqT, wkT, wvT, woT, lds);
    grid.sync();
    for (int t = blockIdx.x; t < PROJ_TILES; t += G)
        proj3_tile(t, qx, kx, vx, wqT, wkT, wvT, bq, bk, bv, qp, kp, vp, lds);
    grid.sync();
    for (int vb = blockIdx.x; vb < ATTN_TILES; vb += G)
        attn_tile(vb, qp, kp, vp, ao);
    grid.sync();
    for (int t = blockIdx.x; t < FINAL_TILES; t += G)
        final_tile(t, ao, woT, bo, out, lds);
}

// ===========================================================================
// Fallback path: round-5 4-kernel pipeline (same phase bodies).
// ===========================================================================
__global__ __launch_bounds__(256) void prep_kernel(
    const float* query, const float* key, const float* value,
    bf16* qx, bf16* kx, bf16* vx,
    const float* wq, const float* wk, const float* wv, const float* wo,
    bf16* wqT, bf16* wkT, bf16* wvT, bf16* woT) {
    __shared__ __align__(16) char lds[4352];   // 32x33 fp32 tile
    prep_work(blockIdx.x, query, key, value, qx, kx, vx,
              wq, wk, wv, wo, wqT, wkT, wvT, woT, lds);
}

__global__ __launch_bounds__(256) void proj3_kernel(
    const bf16* qx, const bf16* kx, const bf16* vx,
    const bf16* wqT, const bf16* wkT, const bf16* wvT,
    const float* bq, const float* bk, const float* bv,
    bf16* qp, bf16* kp, bf16* vp) {
    __shared__ __align__(16) char lds[49152];
    proj3_tile(blockIdx.x, qx, kx, vx, wqT, wkT, wvT, bq, bk, bv,
               qp, kp, vp, lds);
}

__global__ __launch_bounds__(256) void attn_kernel(
    const bf16* qp, const bf16* kp, const bf16* vp, bf16* ao) {
    attn_tile(blockIdx.x, qp, kp, vp, ao);
}

__global__ __launch_bounds__(256) void gemm_final_kernel(
    const bf16* A, const bf16* BT, const float* bias, float* C) {
    __shared__ __align__(16) char lds[49152];
    final_tile(blockIdx.x, A, BT, bias, C, lds);
}

// ---------------------------------------------------------------------------
extern "C" void kernel_launch(void* const* d_in, const int* in_sizes, int n_in,
                              void* d_out, int out_size, void* d_ws, size_t ws_size,
                              hipStream_t stream) {
    const float* query = (const float*)d_in[0];
    const float* key   = (const float*)d_in[1];
    const float* value = (const float*)d_in[2];
    const float* wq = (const float*)d_in[3];
    const float* bq = (const float*)d_in[4];
    const float* wk = (const float*)d_in[5];
    const float* bk = (const float*)d_in[6];
    const float* wv = (const float*)d_in[7];
    const float* bv = (const float*)d_in[8];
    const float* wo = (const float*)d_in[9];
    const float* bo = (const float*)d_in[10];
    float* out = (float*)d_out;

    char* ws = (char*)d_ws;
    auto alloc = [&](size_t bytes) {
        char* p = ws;
        ws += (bytes + 255) & ~(size_t)255;
        return p;
    };
    bf16* qx  = (bf16*)alloc((size_t)SEQ * DMODEL * 2);
    bf16* kx  = (bf16*)alloc((size_t)SEQ * DMODEL * 2);
    bf16* vx  = (bf16*)alloc((size_t)SEQ * DMODEL * 2);
    bf16* wqT = (bf16*)alloc((size_t)DMODEL * DMODEL * 2);
    bf16* wkT = (bf16*)alloc((size_t)DMODEL * DMODEL * 2);
    bf16* wvT = (bf16*)alloc((size_t)DMODEL * DMODEL * 2);
    bf16* woT = (bf16*)alloc((size_t)DMODEL * DMODEL * 2);
    bf16* qp  = (bf16*)alloc((size_t)SEQ * DMODEL * 2);
    bf16* kp  = (bf16*)alloc((size_t)SEQ * DMODEL * 2);
    bf16* vp  = (bf16*)alloc((size_t)SEQ * DMODEL * 2);
    bf16* ao  = (bf16*)alloc((size_t)SEQ * DMODEL * 2);

    // Cooperative grid size: clamp to co-resident capacity (validated by the
    // runtime at launch). LDS 48KB -> 3 blocks/CU -> expect 768.
    static int gridblks = 0;
    static int coop = -1;   // -1 unknown, 1 works, 0 fall back
    if (gridblks == 0) {
        int mb = 0;
        if (hipOccupancyMaxActiveBlocksPerMultiprocessor(&mb, mega_kernel, 256, 0)
                != hipSuccess || mb < 1)
            mb = 1;
        long g = (long)mb * 256;
        if (g > PROJ_TILES) g = PROJ_TILES;
        gridblks = (int)g;
    }

    if (coop != 0) {
        const float *a0 = query, *a1 = key, *a2 = value;
        const float *a3 = wq, *a4 = wk, *a5 = wv, *a6 = wo;
        const float *a7 = bq, *a8 = bk, *a9 = bv, *a10 = bo;
        bf16 *a11 = qx, *a12 = kx, *a13 = vx;
        bf16 *a14 = wqT, *a15 = wkT, *a16 = wvT, *a17 = woT;
        bf16 *a18 = qp, *a19 = kp, *a20 = vp, *a21 = ao;
        float* a22 = out;
        void* args[] = {&a0, &a1, &a2, &a3, &a4, &a5, &a6, &a7, &a8, &a9, &a10,
                        &a11, &a12, &a13, &a14, &a15, &a16, &a17,
                        &a18, &a19, &a20, &a21, &a22};
        hipError_t e = hipLaunchCooperativeKernel(
            (const void*)mega_kernel, dim3(gridblks), dim3(256), args, 0, stream);
        if (e == hipSuccess) { coop = 1; return; }
        coop = 0;
        (void)hipGetLastError();   // clear sticky error, fall through
    }

    // Fallback: round-5 four-kernel pipeline
    prep_kernel<<<dim3(PREP_WORK), 256, 0, stream>>>(
        query, key, value, qx, kx, vx, wq, wk, wv, wo, wqT, wkT, wvT, woT);
    proj3_kernel<<<dim3(PROJ_TILES), 256, 0, stream>>>(
        qx, kx, vx, wqT, wkT, wvT, bq, bk, bv, qp, kp, vp);
    attn_kernel<<<dim3(ATTN_TILES), 256, 0, stream>>>(qp, kp, vp, ao);
    gemm_final_kernel<<<dim3(FINAL_TILES), 256, 0, stream>>>(ao, woT, bo, out);
}

// Round 9
// 160.696 us; speedup vs baseline: 2.0400x; 2.0400x over previous
//
#include <hip/hip_runtime.h>
#include <hip/hip_bf16.h>
#include <cstdint>
#include <math.h>

// Problem constants
#define SEQ    2048
#define DMODEL 1024
#define NHEAD  16
#define DHEAD  64
#define NZPAD  32   // per-row nonzero count padded to 32 (analytic max = 26)

typedef __bf16 bf16;
typedef __bf16 bf16x8 __attribute__((ext_vector_type(8)));
typedef float  f32x4  __attribute__((ext_vector_type(4)));

typedef __attribute__((address_space(3))) uint32_t lds_u32;
typedef __attribute__((address_space(1))) const uint32_t global_u32;

__device__ __forceinline__ void async_load16(const void* g, void* l) {
    __builtin_amdgcn_global_load_lds((global_u32*)g, (lds_u32*)l, 16, 0, 0);
}

// Analytic sparse-layout support for ORIGIN_SHAPE=(8,16,16), LOCAL_BLOCKS=3:
// support(s) = {t'*256 + (s&255), t'<t} u {(s&0x700) + h'*16 + (s&15), h'<h}
//            u {s-win..s}, win = min(s,3); disjoint; cnt = t+h+win+1 <= 26.
__device__ __forceinline__ int support_idx(int s, int c, int tt, int hh,
                                           int cnt) {
    const int jA = c * 256 + (s & 255);                    // axial-T, c < tt
    const int jB = (s & 0x700) + (c - tt) * 16 + (s & 15); // axial-H
    const int jC = s - (cnt - 1 - c);                      // causal window
    return c < tt ? jA : (c < tt + hh ? jB : (c < cnt ? jC : s));
}

// ---------------------------------------------------------------------------
// Merged preprocessing: fp32->bf16 casts of q/k/v (3072 blocks) + weight
// transpose-casts (4096 blocks). Layout support is analytic inside attn.
// Round-4 lesson: keeping the bf16 qx/kx/vx round-trip is a WIN — the
// A-panels get re-read 24x by proj3 blocks, so halving their byte size beats
// saving one 12MB HBM write. Round-6 lesson: no cooperative mega-fusion —
// memory-bound phases need TLP (big grids, separate launches).
#define CAST_BLOCKS 3072
#define TR_BLOCKS   4096

__global__ __launch_bounds__(256) void prep_kernel(
    const float* __restrict__ q, const float* __restrict__ k, const float* __restrict__ v,
    bf16* __restrict__ qx, bf16* __restrict__ kx, bf16* __restrict__ vx,
    const float* __restrict__ w0, const float* __restrict__ w1,
    const float* __restrict__ w2, const float* __restrict__ w3,
    bf16* __restrict__ t0, bf16* __restrict__ t1,
    bf16* __restrict__ t2, bf16* __restrict__ t3) {
    __shared__ float tile[32][33];
    const int bid = blockIdx.x;
    if (bid < CAST_BLOCKS) {
        // ---- fp32 -> bf16 cast of q/k/v (8 elems per thread)
        const int z = bid >> 10;
        const float* src = (z == 0) ? q : (z == 1) ? k : v;
        bf16* dst        = (z == 0) ? qx : (z == 1) ? kx : vx;
        const int i = (bid & 1023) * 256 + threadIdx.x;
        const float4* s4 = (const float4*)src;
        float4 a = s4[i * 2 + 0];
        float4 b = s4[i * 2 + 1];
        bf16x8 o;
        o[0] = (bf16)a.x; o[1] = (bf16)a.y; o[2] = (bf16)a.z; o[3] = (bf16)a.w;
        o[4] = (bf16)b.x; o[5] = (bf16)b.y; o[6] = (bf16)b.z; o[7] = (bf16)b.w;
        ((bf16x8*)dst)[i] = o;
    } else {
        // ---- W[K][N] fp32 -> WT[N][K] bf16
        const int b = bid - CAST_BLOCKS;
        const int z = b >> 10, rem = b & 1023;
        const float* w = (z == 0) ? w0 : (z == 1) ? w1 : (z == 2) ? w2 : w3;
        bf16* t        = (z == 0) ? t0 : (z == 1) ? t1 : (z == 2) ? t2 : t3;
        const int tx = threadIdx.x & 31, ty = threadIdx.x >> 5;
        const int kbase = (rem >> 5) * 32, nbase = (rem & 31) * 32;
#pragma unroll
        for (int i = 0; i < 4; ++i)
            tile[ty + 8 * i][tx] = w[(size_t)(kbase + ty + 8 * i) * DMODEL + nbase + tx];
        __syncthreads();
#pragma unroll
        for (int i = 0; i < 4; ++i)
            t[(size_t)(nbase + ty + 8 * i) * DMODEL + kbase + tx] = (bf16)tile[tx][ty + 8 * i];
    }
}

// ---------------------------------------------------------------------------
// proj3: TM=64, BK=64, 2-deep counted vmcnt(6) pipeline, XOR-swizzled LDS
// (rule #21: inverse-swizzled global source + same XOR on ds_read). 1-D
// grid, XCD-chunked decode: each XCD owns a contiguous run of 96 blocks ->
// working set (12 A-tiles 1.5MB + one BT panel 2MB) fits the private 4MB L2.
__global__ __launch_bounds__(256) void proj3_kernel(
    const bf16* __restrict__ qx, const bf16* __restrict__ kx, const bf16* __restrict__ vx,
    const bf16* __restrict__ wqT, const bf16* __restrict__ wkT, const bf16* __restrict__ wvT,
    const float* __restrict__ bq, const float* __restrict__ bk, const float* __restrict__ bv,
    bf16* __restrict__ qp, bf16* __restrict__ kp, bf16* __restrict__ vp) {
    constexpr int K = 1024, N = 1024, BK = 64, TM = 64, MI = 2;
    constexpr int ACH = TM * (BK / 8);        // 512 chunks
    constexpr int TCH = ACH + 128 * (BK / 8); // 1536 chunks -> 6 per thread

    // XCD-chunked decode (768 blocks, 96 per XCD, bijective: 768 % 8 == 0)
    const int orig = blockIdx.x;
    const int flat = (orig & 7) * 96 + (orig >> 3);
    const int z = flat >> 8;                  // 256 blocks per z
    const int rem = flat & 255;
    const int m0 = (rem >> 3) * TM, n0 = (rem & 7) * 128;

    const bf16* A   = (z == 0) ? qx : (z == 1) ? kx : vx;
    const bf16* BT  = (z == 0) ? wqT : (z == 1) ? wkT : wvT;
    const float* bi = (z == 0) ? bq : (z == 1) ? bk : bv;
    bf16* C         = (z == 0) ? qp : (z == 1) ? kp : vp;

    __shared__ bf16 sA[2][TM * BK];
    __shared__ bf16 sB[2][128 * BK];
    const int tid = threadIdx.x;
    const int w = tid >> 6, lane = tid & 63;
    const int wm = w >> 1, wn = w & 1;
    const int lr = lane & 15, quad = lane >> 4;

    f32x4 acc[MI][4] = {};
    float bia[4];
#pragma unroll
    for (int ni = 0; ni < 4; ++ni) bia[ni] = bi[n0 + wn * 64 + ni * 16 + lr];

    auto stage = [&](int buf, int kt) {
#pragma unroll
        for (int kk = 0; kk < TCH / 256; ++kk) {
            const int cb = kk * 256 + w * 64;     // wave-uniform chunk base
            const int p  = cb + lane;             // linear LDS slot
            if (cb < ACH) {
                const int row = p >> 3, chl = p & 7;
                const int chg = chl ^ (row & 7);  // inverse-swizzled source
                async_load16(A + (size_t)(m0 + row) * K + kt + chg * 8,
                             (char*)&sA[buf][0] + cb * 16);
            } else {
                const int p2 = p - ACH, row = p2 >> 3, chl = p2 & 7;
                const int chg = chl ^ (row & 7);
                async_load16(BT + (size_t)(n0 + row) * K + kt + chg * 8,
                             (char*)&sB[buf][0] + (cb - ACH) * 16);
            }
        }
    };

    stage(0, 0);
    stage(1, BK);
    int cur = 0;
    for (int kt = 0; kt < K; kt += BK) {
        if (kt + BK < K) {
            asm volatile("s_waitcnt vmcnt(6)" ::: "memory");  // cur tile landed
        } else {
            asm volatile("s_waitcnt vmcnt(0)" ::: "memory");  // epilogue drain
        }
        __builtin_amdgcn_s_barrier();
        __builtin_amdgcn_sched_barrier(0);
#pragma unroll
        for (int ks = 0; ks < 2; ++ks) {            // two 16x16x32 k-substeps
            bf16x8 af[MI], bfr[4];
#pragma unroll
            for (int mi = 0; mi < MI; ++mi) {
                const int row = wm * (TM / 2) + mi * 16 + lr;
                af[mi] = *(const bf16x8*)
                    &sA[cur][row * BK + ((ks * 4 + quad) ^ (row & 7)) * 8];
            }
#pragma unroll
            for (int ni = 0; ni < 4; ++ni) {
                const int row = wn * 64 + ni * 16 + lr;
                bfr[ni] = *(const bf16x8*)
                    &sB[cur][row * BK + ((ks * 4 + quad) ^ (row & 7)) * 8];
            }
            __builtin_amdgcn_s_setprio(1);
#pragma unroll
            for (int mi = 0; mi < MI; ++mi)
#pragma unroll
                for (int ni = 0; ni < 4; ++ni)
                    acc[mi][ni] = __builtin_amdgcn_mfma_f32_16x16x32_bf16(
                        af[mi], bfr[ni], acc[mi][ni], 0, 0, 0);
            __builtin_amdgcn_s_setprio(0);
        }
        __builtin_amdgcn_s_barrier();               // all waves done reading cur
        __builtin_amdgcn_sched_barrier(0);
        if (kt + 2 * BK < K) stage(cur, kt + 2 * BK);  // restage freed buffer
        cur ^= 1;
    }

#pragma unroll
    for (int mi = 0; mi < MI; ++mi)
#pragma unroll
        for (int ni = 0; ni < 4; ++ni) {
            const int row = m0 + wm * (TM / 2) + mi * 16 + quad * 4;
            const int col = n0 + wn * 64 + ni * 16 + lr;
            const f32x4 vv = acc[mi][ni];
#pragma unroll
            for (int r = 0; r < 4; ++r)
                C[(size_t)(row + r) * N + col] = (bf16)(vv[r] + bia[ni]);
        }
}

// ---------------------------------------------------------------------------
// Final GEMM: C_f32 = A_bf16 @ BT^T + bias. TM=32 (512 blocks = 2/CU) with
// 1x4 wave grid (wave-tile 32x32: 4 ds_read_b128 per substep). 2-deep
// counted pipeline (5 loads/stage -> vmcnt(5)). XCD-chunked decode.
__global__ __launch_bounds__(256) void gemm_final_kernel(
    const bf16* __restrict__ A, const bf16* __restrict__ BT,
    const float* __restrict__ bias, float* __restrict__ C) {
    constexpr int K = 1024, N = 1024, BK = 64, TM = 32, MI = 2;
    constexpr int ACH = TM * (BK / 8);        // 256 chunks
    constexpr int TCH = ACH + 128 * (BK / 8); // 1280 chunks -> 5 per thread

    const int orig = blockIdx.x;              // 512 blocks, 64 per XCD
    const int flat = (orig & 7) * 64 + (orig >> 3);
    const int m0 = (flat >> 3) * TM, n0 = (flat & 7) * 128;

    __shared__ bf16 sA[2][TM * BK];
    __shared__ bf16 sB[2][128 * BK];
    const int tid = threadIdx.x;
    const int w = tid >> 6, lane = tid & 63;  // wn = w (1x4 wave grid)
    const int lr = lane & 15, quad = lane >> 4;

    f32x4 acc[MI][2] = {};
    float bia[2];
#pragma unroll
    for (int ni = 0; ni < 2; ++ni) bia[ni] = bias[n0 + w * 32 + ni * 16 + lr];

    auto stage = [&](int buf, int kt) {
#pragma unroll
        for (int kk = 0; kk < TCH / 256; ++kk) {
            const int cb = kk * 256 + w * 64;
            const int p = cb + lane;
            if (cb < ACH) {
                const int row = p >> 3, chl = p & 7;
                const int chg = chl ^ (row & 7);
                async_load16(A + (size_t)(m0 + row) * K + kt + chg * 8,
                             (char*)&sA[buf][0] + cb * 16);
            } else {
                const int p2 = p - ACH, row = p2 >> 3, chl = p2 & 7;
                const int chg = chl ^ (row & 7);
                async_load16(BT + (size_t)(n0 + row) * K + kt + chg * 8,
                             (char*)&sB[buf][0] + (cb - ACH) * 16);
            }
        }
    };

    stage(0, 0);
    stage(1, BK);
    int cur = 0;
    for (int kt = 0; kt < K; kt += BK) {
        if (kt + BK < K) {
            asm volatile("s_waitcnt vmcnt(5)" ::: "memory");
        } else {
            asm volatile("s_waitcnt vmcnt(0)" ::: "memory");
        }
        __builtin_amdgcn_s_barrier();
        __builtin_amdgcn_sched_barrier(0);
#pragma unroll
        for (int ks = 0; ks < 2; ++ks) {
            bf16x8 af[MI], bfr[2];
#pragma unroll
            for (int mi = 0; mi < MI; ++mi) {
                const int row = mi * 16 + lr;
                af[mi] = *(const bf16x8*)
                    &sA[cur][row * BK + ((ks * 4 + quad) ^ (row & 7)) * 8];
            }
#pragma unroll
            for (int ni = 0; ni < 2; ++ni) {
                const int row = w * 32 + ni * 16 + lr;
                bfr[ni] = *(const bf16x8*)
                    &sB[cur][row * BK + ((ks * 4 + quad) ^ (row & 7)) * 8];
            }
            __builtin_amdgcn_s_setprio(1);
#pragma unroll
            for (int mi = 0; mi < MI; ++mi)
#pragma unroll
                for (int ni = 0; ni < 2; ++ni)
                    acc[mi][ni] = __builtin_amdgcn_mfma_f32_16x16x32_bf16(
                        af[mi], bfr[ni], acc[mi][ni], 0, 0, 0);
            __builtin_amdgcn_s_setprio(0);
        }
        __builtin_amdgcn_s_barrier();
        __builtin_amdgcn_sched_barrier(0);
        if (kt + 2 * BK < K) stage(cur, kt + 2 * BK);
        cur ^= 1;
    }

#pragma unroll
    for (int mi = 0; mi < MI; ++mi)
#pragma unroll
        for (int ni = 0; ni < 2; ++ni) {
            const int row = m0 + mi * 16 + quad * 4;
            const int col = n0 + w * 32 + ni * 16 + lr;
            const f32x4 vv = acc[mi][ni];
#pragma unroll
            for (int r = 0; r < 4; ++r)
                C[(size_t)(row + r) * N + col] = vv[r] + bia[ni];
        }
}

// ---------------------------------------------------------------------------
// Sparse attention: analytic support in-register (no nzidx memory),
// lane=candidate QK layout, XCD-chunked block swizzle (2 heads = 1.5MB per
// XCD fits private L2), setprio around the FMA clusters.
__global__ __launch_bounds__(256) void attn_kernel(
    const bf16* __restrict__ qp, const bf16* __restrict__ kp, const bf16* __restrict__ vp,
    bf16* __restrict__ ao) {
    const int wv = threadIdx.x >> 6, lane = threadIdx.x & 63;
    constexpr int NB = NHEAD * SEQ / 4;           // 8192 blocks
    const int bid = (blockIdx.x & 7) * (NB >> 3) + (blockIdx.x >> 3);
    const int p = bid * 4 + wv;
    const int s = __builtin_amdgcn_readfirstlane(p & (SEQ - 1));
    const int h = __builtin_amdgcn_readfirstlane(p >> 11);
    const int hbase = h * DHEAD;
    const int hoff = hbase + lane;

    const int tt = (s >> 8) & 7, hh = (s >> 4) & 15;
    const int win = (s < 3) ? s : 3;
    const int cnt = tt + hh + win + 1;

    int t[NZPAD];                                  // s-uniform -> scalar regs
#pragma unroll
    for (int c = 0; c < NZPAD; ++c) t[c] = support_idx(s, c, tt, hh, cnt);

    // --- QK^T, lane=candidate
    const int c_lane = lane & 31;
    const int fo = (lane >> 5) << 5;               // feature offset: 0 or 32
    const int myT = support_idx(s, c_lane, tt, hh, cnt);  // per-lane (VALU)

    const bf16x8* qrow = (const bf16x8*)(qp + (size_t)s * DMODEL + hbase + fo);
    const bf16x8* krow = (const bf16x8*)(kp + (size_t)myT * DMODEL + hbase + fo);
    bf16x8 qc[4], kc[4];
#pragma unroll
    for (int j = 0; j < 4; ++j) { qc[j] = qrow[j]; kc[j] = krow[j]; }

    // hoist V loads (independent of softmax) to overlap latency; lane=feature
    float vvv[NZPAD];
#pragma unroll
    for (int c = 0; c < NZPAD; ++c)
        vvv[c] = (float)vp[(size_t)t[c] * DMODEL + hoff];

    float dot = 0.f;
    __builtin_amdgcn_s_setprio(1);
#pragma unroll
    for (int j = 0; j < 4; ++j)
#pragma unroll
        for (int e = 0; e < 8; ++e)
            dot = fmaf((float)qc[j][e], (float)kc[j][e], dot);
    __builtin_amdgcn_s_setprio(0);
    dot += __shfl_xor(dot, 32);   // combine feature halves -> full dot in lane c

    const float logit = (c_lane < cnt) ? dot * 0.125f : -1e30f;  // 1/sqrt(64)
    float m = logit;
    m = fmaxf(m, __shfl_xor(m, 1)); m = fmaxf(m, __shfl_xor(m, 2));
    m = fmaxf(m, __shfl_xor(m, 4)); m = fmaxf(m, __shfl_xor(m, 8));
    m = fmaxf(m, __shfl_xor(m, 16));
    const float e = __expf(logit - m);
    float ssum = e;
    ssum += __shfl_xor(ssum, 1); ssum += __shfl_xor(ssum, 2);
    ssum += __shfl_xor(ssum, 4); ssum += __shfl_xor(ssum, 8);
    ssum += __shfl_xor(ssum, 16);
    const float prob = e / ssum;

    float acc = 0.f;
    __builtin_amdgcn_s_setprio(1);
#pragma unroll
    for (int c = 0; c < NZPAD; ++c) {
        const float pc = __uint_as_float(
            __builtin_amdgcn_readlane(__float_as_uint(prob), c));
        acc = fmaf(pc, vvv[c], acc);
    }
    __builtin_amdgcn_s_setprio(0);
    ao[(size_t)s * DMODEL + hoff] = (bf16)acc;
}

// ---------------------------------------------------------------------------
extern "C" void kernel_launch(void* const* d_in, const int* in_sizes, int n_in,
                              void* d_out, int out_size, void* d_ws, size_t ws_size,
                              hipStream_t stream) {
    const float* query = (const float*)d_in[0];
    const float* key   = (const float*)d_in[1];
    const float* value = (const float*)d_in[2];
    const float* wq = (const float*)d_in[3];
    const float* bq = (const float*)d_in[4];
    const float* wk = (const float*)d_in[5];
    const float* bk = (const float*)d_in[6];
    const float* wv = (const float*)d_in[7];
    const float* bv = (const float*)d_in[8];
    const float* wo = (const float*)d_in[9];
    const float* bo = (const float*)d_in[10];
    float* out = (float*)d_out;

    char* ws = (char*)d_ws;
    auto alloc = [&](size_t bytes) {
        char* p = ws;
        ws += (bytes + 255) & ~(size_t)255;
        return p;
    };
    bf16* qx  = (bf16*)alloc((size_t)SEQ * DMODEL * 2);
    bf16* kx  = (bf16*)alloc((size_t)SEQ * DMODEL * 2);
    bf16* vx  = (bf16*)alloc((size_t)SEQ * DMODEL * 2);
    bf16* wqT = (bf16*)alloc((size_t)DMODEL * DMODEL * 2);
    bf16* wkT = (bf16*)alloc((size_t)DMODEL * DMODEL * 2);
    bf16* wvT = (bf16*)alloc((size_t)DMODEL * DMODEL * 2);
    bf16* woT = (bf16*)alloc((size_t)DMODEL * DMODEL * 2);
    bf16* qp  = (bf16*)alloc((size_t)SEQ * DMODEL * 2);
    bf16* kp  = (bf16*)alloc((size_t)SEQ * DMODEL * 2);
    bf16* vp  = (bf16*)alloc((size_t)SEQ * DMODEL * 2);
    bf16* ao  = (bf16*)alloc((size_t)SEQ * DMODEL * 2);

    // 1. merged prep: q/k/v casts + weight transposes (layout is analytic)
    prep_kernel<<<dim3(CAST_BLOCKS + TR_BLOCKS), 256, 0, stream>>>(
        query, key, value, qx, kx, vx,
        wq, wk, wv, wo, wqT, wkT, wvT, woT);
    // 2. q/k/v projections (768 blocks, XCD-chunked 1-D grid)
    proj3_kernel<<<dim3(768), 256, 0, stream>>>(
        qx, kx, vx, wqT, wkT, wvT, bq, bk, bv, qp, kp, vp);
    // 3. sparse attention (analytic support, XCD-chunked swizzle)
    attn_kernel<<<dim3(NHEAD * SEQ / 4), 256, 0, stream>>>(qp, kp, vp, ao);
    // 4. output projection to fp32 (512 blocks, XCD-chunked 1-D grid)
    gemm_final_kernel<<<dim3(512), 256, 0, stream>>>(ao, woT, bo, out);
}

// Round 10
// 160.386 us; speedup vs baseline: 2.0440x; 1.0019x over previous
//
#include <hip/hip_runtime.h>
#include <hip/hip_bf16.h>
#include <cstdint>
#include <math.h>

// Problem constants
#define SEQ    2048
#define DMODEL 1024
#define NHEAD  16
#define DHEAD  64
#define NZPAD  32   // per-row nonzero count padded to 32 (analytic max = 26)

typedef __bf16 bf16;
typedef __bf16 bf16x4 __attribute__((ext_vector_type(4)));
typedef __bf16 bf16x8 __attribute__((ext_vector_type(8)));
typedef float  f32x4  __attribute__((ext_vector_type(4)));

typedef __attribute__((address_space(3))) uint32_t lds_u32;
typedef __attribute__((address_space(1))) const uint32_t global_u32;

__device__ __forceinline__ void async_load16(const void* g, void* l) {
    __builtin_amdgcn_global_load_lds((global_u32*)g, (lds_u32*)l, 16, 0, 0);
}

// Analytic sparse-layout support for ORIGIN_SHAPE=(8,16,16), LOCAL_BLOCKS=3:
// support(s) = {t'*256 + (s&255), t'<t} u {(s&0x700) + h'*16 + (s&15), h'<h}
//            u {s-win..s}, win = min(s,3); disjoint; cnt = t+h+win+1 <= 26.
__device__ __forceinline__ int support_idx(int s, int c, int tt, int hh,
                                           int cnt) {
    const int jA = c * 256 + (s & 255);                    // axial-T, c < tt
    const int jB = (s & 0x700) + (c - tt) * 16 + (s & 15); // axial-H
    const int jC = s - (cnt - 1 - c);                      // causal window
    return c < tt ? jA : (c < tt + hh ? jB : (c < cnt ? jC : s));
}

// ---------------------------------------------------------------------------
// Merged preprocessing.
//  - cast section: 1536 blocks, 16 elems/thread (4x float4 -> 2x bf16x8).
//  - TR section: 1024 blocks, 64x64 float4 tiles (round-4-verified body;
//    the old 32x32 body used SCALAR 4B loads — G13 violation, ~2x slower
//    on the same bytes, 4x the blocks).
// Round-4 lesson: keep the bf16 qx/kx/vx round-trip (A-panels re-read by
// many blocks; halving their size beats saving one write). Round-6 lesson:
// no cooperative mega-fusion (memory-bound phases need TLP).
#define CAST_BLOCKS 1536
#define TR_BLOCKS   1024

__global__ __launch_bounds__(256) void prep_kernel(
    const float* __restrict__ q, const float* __restrict__ k, const float* __restrict__ v,
    bf16* __restrict__ qx, bf16* __restrict__ kx, bf16* __restrict__ vx,
    const float* __restrict__ w0, const float* __restrict__ w1,
    const float* __restrict__ w2, const float* __restrict__ w3,
    bf16* __restrict__ t0, bf16* __restrict__ t1,
    bf16* __restrict__ t2, bf16* __restrict__ t3) {
    __shared__ float tile[64][65];
    const int bid = blockIdx.x;
    if (bid < CAST_BLOCKS) {
        // ---- fp32 -> bf16 cast of q/k/v (16 elems per thread)
        const int z = bid >> 9;                   // 512 blocks per tensor
        const float* src = (z == 0) ? q : (z == 1) ? k : v;
        bf16* dst        = (z == 0) ? qx : (z == 1) ? kx : vx;
        const int i = (bid & 511) * 256 + threadIdx.x;
        const float4* s4 = (const float4*)src;
        float4 a0 = s4[i * 4 + 0];
        float4 a1 = s4[i * 4 + 1];
        float4 a2 = s4[i * 4 + 2];
        float4 a3 = s4[i * 4 + 3];
        bf16x8 o0, o1;
        o0[0] = (bf16)a0.x; o0[1] = (bf16)a0.y; o0[2] = (bf16)a0.z; o0[3] = (bf16)a0.w;
        o0[4] = (bf16)a1.x; o0[5] = (bf16)a1.y; o0[6] = (bf16)a1.z; o0[7] = (bf16)a1.w;
        o1[0] = (bf16)a2.x; o1[1] = (bf16)a2.y; o1[2] = (bf16)a2.z; o1[3] = (bf16)a2.w;
        o1[4] = (bf16)a3.x; o1[5] = (bf16)a3.y; o1[6] = (bf16)a3.z; o1[7] = (bf16)a3.w;
        ((bf16x8*)dst)[i * 2 + 0] = o0;
        ((bf16x8*)dst)[i * 2 + 1] = o1;
    } else {
        // ---- W[K][N] fp32 -> WT[N][K] bf16, 64x64 tile, float4 I/O
        const int b = bid - CAST_BLOCKS;
        const int z = b >> 8, rem = b & 255;
        const float* w = (z == 0) ? w0 : (z == 1) ? w1 : (z == 2) ? w2 : w3;
        bf16* t        = (z == 0) ? t0 : (z == 1) ? t1 : (z == 2) ? t2 : t3;
        const int kb = (rem >> 4) * 64, nb = (rem & 15) * 64;
        const int c4 = threadIdx.x & 15, rg = threadIdx.x >> 4;
#pragma unroll
        for (int i = 0; i < 4; ++i) {
            const int row = rg * 4 + i;
            const float4 vv = *(const float4*)&w[(size_t)(kb + row) * DMODEL + nb + c4 * 4];
            tile[row][c4 * 4 + 0] = vv.x; tile[row][c4 * 4 + 1] = vv.y;
            tile[row][c4 * 4 + 2] = vv.z; tile[row][c4 * 4 + 3] = vv.w;
        }
        __syncthreads();
#pragma unroll
        for (int i = 0; i < 4; ++i) {
            const int n = rg * 4 + i;
            bf16x4 o;
            o[0] = (bf16)tile[c4 * 4 + 0][n]; o[1] = (bf16)tile[c4 * 4 + 1][n];
            o[2] = (bf16)tile[c4 * 4 + 2][n]; o[3] = (bf16)tile[c4 * 4 + 3][n];
            *(bf16x4*)&t[(size_t)(nb + n) * DMODEL + kb + c4 * 4] = o;
        }
    }
}

// ---------------------------------------------------------------------------
// proj3: TM=64, BK=64, 2-deep counted vmcnt(6) pipeline, XOR-swizzled LDS
// (rule #21: inverse-swizzled global source + same XOR on ds_read). 1-D
// grid, XCD-chunked decode: each XCD owns a contiguous run of 96 blocks ->
// working set (12 A-tiles 1.5MB + one BT panel 2MB) fits the private 4MB L2.
__global__ __launch_bounds__(256) void proj3_kernel(
    const bf16* __restrict__ qx, const bf16* __restrict__ kx, const bf16* __restrict__ vx,
    const bf16* __restrict__ wqT, const bf16* __restrict__ wkT, const bf16* __restrict__ wvT,
    const float* __restrict__ bq, const float* __restrict__ bk, const float* __restrict__ bv,
    bf16* __restrict__ qp, bf16* __restrict__ kp, bf16* __restrict__ vp) {
    constexpr int K = 1024, N = 1024, BK = 64, TM = 64, MI = 2;
    constexpr int ACH = TM * (BK / 8);        // 512 chunks
    constexpr int TCH = ACH + 128 * (BK / 8); // 1536 chunks -> 6 per thread

    // XCD-chunked decode (768 blocks, 96 per XCD, bijective: 768 % 8 == 0)
    const int orig = blockIdx.x;
    const int flat = (orig & 7) * 96 + (orig >> 3);
    const int z = flat >> 8;                  // 256 blocks per z
    const int rem = flat & 255;
    const int m0 = (rem >> 3) * TM, n0 = (rem & 7) * 128;

    const bf16* A   = (z == 0) ? qx : (z == 1) ? kx : vx;
    const bf16* BT  = (z == 0) ? wqT : (z == 1) ? wkT : wvT;
    const float* bi = (z == 0) ? bq : (z == 1) ? bk : bv;
    bf16* C         = (z == 0) ? qp : (z == 1) ? kp : vp;

    __shared__ bf16 sA[2][TM * BK];
    __shared__ bf16 sB[2][128 * BK];
    const int tid = threadIdx.x;
    const int w = tid >> 6, lane = tid & 63;
    const int wm = w >> 1, wn = w & 1;
    const int lr = lane & 15, quad = lane >> 4;

    f32x4 acc[MI][4] = {};
    float bia[4];
#pragma unroll
    for (int ni = 0; ni < 4; ++ni) bia[ni] = bi[n0 + wn * 64 + ni * 16 + lr];

    auto stage = [&](int buf, int kt) {
#pragma unroll
        for (int kk = 0; kk < TCH / 256; ++kk) {
            const int cb = kk * 256 + w * 64;     // wave-uniform chunk base
            const int p  = cb + lane;             // linear LDS slot
            if (cb < ACH) {
                const int row = p >> 3, chl = p & 7;
                const int chg = chl ^ (row & 7);  // inverse-swizzled source
                async_load16(A + (size_t)(m0 + row) * K + kt + chg * 8,
                             (char*)&sA[buf][0] + cb * 16);
            } else {
                const int p2 = p - ACH, row = p2 >> 3, chl = p2 & 7;
                const int chg = chl ^ (row & 7);
                async_load16(BT + (size_t)(n0 + row) * K + kt + chg * 8,
                             (char*)&sB[buf][0] + (cb - ACH) * 16);
            }
        }
    };

    stage(0, 0);
    stage(1, BK);
    int cur = 0;
    for (int kt = 0; kt < K; kt += BK) {
        if (kt + BK < K) {
            asm volatile("s_waitcnt vmcnt(6)" ::: "memory");  // cur tile landed
        } else {
            asm volatile("s_waitcnt vmcnt(0)" ::: "memory");  // epilogue drain
        }
        __builtin_amdgcn_s_barrier();
        __builtin_amdgcn_sched_barrier(0);
#pragma unroll
        for (int ks = 0; ks < 2; ++ks) {            // two 16x16x32 k-substeps
            bf16x8 af[MI], bfr[4];
#pragma unroll
            for (int mi = 0; mi < MI; ++mi) {
                const int row = wm * (TM / 2) + mi * 16 + lr;
                af[mi] = *(const bf16x8*)
                    &sA[cur][row * BK + ((ks * 4 + quad) ^ (row & 7)) * 8];
            }
#pragma unroll
            for (int ni = 0; ni < 4; ++ni) {
                const int row = wn * 64 + ni * 16 + lr;
                bfr[ni] = *(const bf16x8*)
                    &sB[cur][row * BK + ((ks * 4 + quad) ^ (row & 7)) * 8];
            }
            __builtin_amdgcn_s_setprio(1);
#pragma unroll
            for (int mi = 0; mi < MI; ++mi)
#pragma unroll
                for (int ni = 0; ni < 4; ++ni)
                    acc[mi][ni] = __builtin_amdgcn_mfma_f32_16x16x32_bf16(
                        af[mi], bfr[ni], acc[mi][ni], 0, 0, 0);
            __builtin_amdgcn_s_setprio(0);
        }
        __builtin_amdgcn_s_barrier();               // all waves done reading cur
        __builtin_amdgcn_sched_barrier(0);
        if (kt + 2 * BK < K) stage(cur, kt + 2 * BK);  // restage freed buffer
        cur ^= 1;
    }

#pragma unroll
    for (int mi = 0; mi < MI; ++mi)
#pragma unroll
        for (int ni = 0; ni < 4; ++ni) {
            const int row = m0 + wm * (TM / 2) + mi * 16 + quad * 4;
            const int col = n0 + wn * 64 + ni * 16 + lr;
            const f32x4 vv = acc[mi][ni];
#pragma unroll
            for (int r = 0; r < 4; ++r)
                C[(size_t)(row + r) * N + col] = (bf16)(vv[r] + bia[ni]);
        }
}

// ---------------------------------------------------------------------------
// Final GEMM: C_f32 = A_bf16 @ BT^T + bias. TM=32 (512 blocks = 2/CU) with
// 1x4 wave grid (wave-tile 32x32: 4 ds_read_b128 per substep). 2-deep
// counted pipeline (5 loads/stage -> vmcnt(5)). XCD-chunked decode.
__global__ __launch_bounds__(256) void gemm_final_kernel(
    const bf16* __restrict__ A, const bf16* __restrict__ BT,
    const float* __restrict__ bias, float* __restrict__ C) {
    constexpr int K = 1024, N = 1024, BK = 64, TM = 32, MI = 2;
    constexpr int ACH = TM * (BK / 8);        // 256 chunks
    constexpr int TCH = ACH + 128 * (BK / 8); // 1280 chunks -> 5 per thread

    const int orig = blockIdx.x;              // 512 blocks, 64 per XCD
    const int flat = (orig & 7) * 64 + (orig >> 3);
    const int m0 = (flat >> 3) * TM, n0 = (flat & 7) * 128;

    __shared__ bf16 sA[2][TM * BK];
    __shared__ bf16 sB[2][128 * BK];
    const int tid = threadIdx.x;
    const int w = tid >> 6, lane = tid & 63;  // wn = w (1x4 wave grid)
    const int lr = lane & 15, quad = lane >> 4;

    f32x4 acc[MI][2] = {};
    float bia[2];
#pragma unroll
    for (int ni = 0; ni < 2; ++ni) bia[ni] = bias[n0 + w * 32 + ni * 16 + lr];

    auto stage = [&](int buf, int kt) {
#pragma unroll
        for (int kk = 0; kk < TCH / 256; ++kk) {
            const int cb = kk * 256 + w * 64;
            const int p = cb + lane;
            if (cb < ACH) {
                const int row = p >> 3, chl = p & 7;
                const int chg = chl ^ (row & 7);
                async_load16(A + (size_t)(m0 + row) * K + kt + chg * 8,
                             (char*)&sA[buf][0] + cb * 16);
            } else {
                const int p2 = p - ACH, row = p2 >> 3, chl = p2 & 7;
                const int chg = chl ^ (row & 7);
                async_load16(BT + (size_t)(n0 + row) * K + kt + chg * 8,
                             (char*)&sB[buf][0] + (cb - ACH) * 16);
            }
        }
    };

    stage(0, 0);
    stage(1, BK);
    int cur = 0;
    for (int kt = 0; kt < K; kt += BK) {
        if (kt + BK < K) {
            asm volatile("s_waitcnt vmcnt(5)" ::: "memory");
        } else {
            asm volatile("s_waitcnt vmcnt(0)" ::: "memory");
        }
        __builtin_amdgcn_s_barrier();
        __builtin_amdgcn_sched_barrier(0);
#pragma unroll
        for (int ks = 0; ks < 2; ++ks) {
            bf16x8 af[MI], bfr[2];
#pragma unroll
            for (int mi = 0; mi < MI; ++mi) {
                const int row = mi * 16 + lr;
                af[mi] = *(const bf16x8*)
                    &sA[cur][row * BK + ((ks * 4 + quad) ^ (row & 7)) * 8];
            }
#pragma unroll
            for (int ni = 0; ni < 2; ++ni) {
                const int row = w * 32 + ni * 16 + lr;
                bfr[ni] = *(const bf16x8*)
                    &sB[cur][row * BK + ((ks * 4 + quad) ^ (row & 7)) * 8];
            }
            __builtin_amdgcn_s_setprio(1);
#pragma unroll
            for (int mi = 0; mi < MI; ++mi)
#pragma unroll
                for (int ni = 0; ni < 2; ++ni)
                    acc[mi][ni] = __builtin_amdgcn_mfma_f32_16x16x32_bf16(
                        af[mi], bfr[ni], acc[mi][ni], 0, 0, 0);
            __builtin_amdgcn_s_setprio(0);
        }
        __builtin_amdgcn_s_barrier();
        __builtin_amdgcn_sched_barrier(0);
        if (kt + 2 * BK < K) stage(cur, kt + 2 * BK);
        cur ^= 1;
    }

#pragma unroll
    for (int mi = 0; mi < MI; ++mi)
#pragma unroll
        for (int ni = 0; ni < 2; ++ni) {
            const int row = m0 + mi * 16 + quad * 4;
            const int col = n0 + w * 32 + ni * 16 + lr;
            const f32x4 vv = acc[mi][ni];
#pragma unroll
            for (int r = 0; r < 4; ++r)
                C[(size_t)(row + r) * N + col] = vv[r] + bia[ni];
        }
}

// ---------------------------------------------------------------------------
// Sparse attention: analytic support in-register (no nzidx memory),
// lane=candidate QK layout, XCD-chunked block swizzle (2 heads = 1.5MB per
// XCD fits private L2), setprio around the FMA clusters.
__global__ __launch_bounds__(256) void attn_kernel(
    const bf16* __restrict__ qp, const bf16* __restrict__ kp, const bf16* __restrict__ vp,
    bf16* __restrict__ ao) {
    const int wv = threadIdx.x >> 6, lane = threadIdx.x & 63;
    constexpr int NB = NHEAD * SEQ / 4;           // 8192 blocks
    const int bid = (blockIdx.x & 7) * (NB >> 3) + (blockIdx.x >> 3);
    const int p = bid * 4 + wv;
    const int s = __builtin_amdgcn_readfirstlane(p & (SEQ - 1));
    const int h = __builtin_amdgcn_readfirstlane(p >> 11);
    const int hbase = h * DHEAD;
    const int hoff = hbase + lane;

    const int tt = (s >> 8) & 7, hh = (s >> 4) & 15;
    const int win = (s < 3) ? s : 3;
    const int cnt = tt + hh + win + 1;

    int t[NZPAD];                                  // s-uniform -> scalar regs
#pragma unroll
    for (int c = 0; c < NZPAD; ++c) t[c] = support_idx(s, c, tt, hh, cnt);

    // --- QK^T, lane=candidate
    const int c_lane = lane & 31;
    const int fo = (lane >> 5) << 5;               // feature offset: 0 or 32
    const int myT = support_idx(s, c_lane, tt, hh, cnt);  // per-lane (VALU)

    const bf16x8* qrow = (const bf16x8*)(qp + (size_t)s * DMODEL + hbase + fo);
    const bf16x8* krow = (const bf16x8*)(kp + (size_t)myT * DMODEL + hbase + fo);
    bf16x8 qc[4], kc[4];
#pragma unroll
    for (int j = 0; j < 4; ++j) { qc[j] = qrow[j]; kc[j] = krow[j]; }

    // hoist V loads (independent of softmax) to overlap latency; lane=feature
    float vvv[NZPAD];
#pragma unroll
    for (int c = 0; c < NZPAD; ++c)
        vvv[c] = (float)vp[(size_t)t[c] * DMODEL + hoff];

    float dot = 0.f;
    __builtin_amdgcn_s_setprio(1);
#pragma unroll
    for (int j = 0; j < 4; ++j)
#pragma unroll
        for (int e = 0; e < 8; ++e)
            dot = fmaf((float)qc[j][e], (float)kc[j][e], dot);
    __builtin_amdgcn_s_setprio(0);
    dot += __shfl_xor(dot, 32);   // combine feature halves -> full dot in lane c

    const float logit = (c_lane < cnt) ? dot * 0.125f : -1e30f;  // 1/sqrt(64)
    float m = logit;
    m = fmaxf(m, __shfl_xor(m, 1)); m = fmaxf(m, __shfl_xor(m, 2));
    m = fmaxf(m, __shfl_xor(m, 4)); m = fmaxf(m, __shfl_xor(m, 8));
    m = fmaxf(m, __shfl_xor(m, 16));
    const float e = __expf(logit - m);
    float ssum = e;
    ssum += __shfl_xor(ssum, 1); ssum += __shfl_xor(ssum, 2);
    ssum += __shfl_xor(ssum, 4); ssum += __shfl_xor(ssum, 8);
    ssum += __shfl_xor(ssum, 16);
    const float prob = e / ssum;

    float acc = 0.f;
    __builtin_amdgcn_s_setprio(1);
#pragma unroll
    for (int c = 0; c < NZPAD; ++c) {
        const float pc = __uint_as_float(
            __builtin_amdgcn_readlane(__float_as_uint(prob), c));
        acc = fmaf(pc, vvv[c], acc);
    }
    __builtin_amdgcn_s_setprio(0);
    ao[(size_t)s * DMODEL + hoff] = (bf16)acc;
}

// ---------------------------------------------------------------------------
extern "C" void kernel_launch(void* const* d_in, const int* in_sizes, int n_in,
                              void* d_out, int out_size, void* d_ws, size_t ws_size,
                              hipStream_t stream) {
    const float* query = (const float*)d_in[0];
    const float* key   = (const float*)d_in[1];
    const float* value = (const float*)d_in[2];
    const float* wq = (const float*)d_in[3];
    const float* bq = (const float*)d_in[4];
    const float* wk = (const float*)d_in[5];
    const float* bk = (const float*)d_in[6];
    const float* wv = (const float*)d_in[7];
    const float* bv = (const float*)d_in[8];
    const float* wo = (const float*)d_in[9];
    const float* bo = (const float*)d_in[10];
    float* out = (float*)d_out;

    char* ws = (char*)d_ws;
    auto alloc = [&](size_t bytes) {
        char* p = ws;
        ws += (bytes + 255) & ~(size_t)255;
        return p;
    };
    bf16* qx  = (bf16*)alloc((size_t)SEQ * DMODEL * 2);
    bf16* kx  = (bf16*)alloc((size_t)SEQ * DMODEL * 2);
    bf16* vx  = (bf16*)alloc((size_t)SEQ * DMODEL * 2);
    bf16* wqT = (bf16*)alloc((size_t)DMODEL * DMODEL * 2);
    bf16* wkT = (bf16*)alloc((size_t)DMODEL * DMODEL * 2);
    bf16* wvT = (bf16*)alloc((size_t)DMODEL * DMODEL * 2);
    bf16* woT = (bf16*)alloc((size_t)DMODEL * DMODEL * 2);
    bf16* qp  = (bf16*)alloc((size_t)SEQ * DMODEL * 2);
    bf16* kp  = (bf16*)alloc((size_t)SEQ * DMODEL * 2);
    bf16* vp  = (bf16*)alloc((size_t)SEQ * DMODEL * 2);
    bf16* ao  = (bf16*)alloc((size_t)SEQ * DMODEL * 2);

    // 1. merged prep: vectorized casts + 64x64 float4 weight transposes
    prep_kernel<<<dim3(CAST_BLOCKS + TR_BLOCKS), 256, 0, stream>>>(
        query, key, value, qx, kx, vx,
        wq, wk, wv, wo, wqT, wkT, wvT, woT);
    // 2. q/k/v projections (768 blocks, XCD-chunked 1-D grid)
    proj3_kernel<<<dim3(768), 256, 0, stream>>>(
        qx, kx, vx, wqT, wkT, wvT, bq, bk, bv, qp, kp, vp);
    // 3. sparse attention (analytic support, XCD-chunked swizzle)
    attn_kernel<<<dim3(NHEAD * SEQ / 4), 256, 0, stream>>>(qp, kp, vp, ao);
    // 4. output projection to fp32 (512 blocks, XCD-chunked 1-D grid)
    gemm_final_kernel<<<dim3(512), 256, 0, stream>>>(ao, woT, bo, out);
}